// Round 1
// baseline (216.903 us; speedup 1.0000x reference)
//
#include <hip/hip_runtime.h>
#include <hip/hip_bf16.h>

// Problem: B=2, L=256, D=128, H=256 fast-weight (TTT-style) forward.
// Exact rewrite: sequential momentum/weight-decay scan -> decay-weighted
// attention with composed decay matrix S = wd_cs @ mom_cs computed by a
// stable O(L^2) recurrence (all exp() arguments <= 0).

#define Bc 2
#define Lc 256
#define Dc 128
#define Hc 256

__device__ __forceinline__ float sigf(float z)  { return 1.f / (1.f + expf(-z)); }
__device__ __forceinline__ float siluf(float z) { return z * sigf(z); }
// NOTE: replicates reference silu_backward exactly: s + sigmoid(z)*(1-s), s=silu(z)
__device__ __forceinline__ float silubwdf(float z) {
    float sg = sigf(z);
    float s  = z * sg;
    return s + sg * (1.f - s);
}
__device__ __forceinline__ float softplusf(float z) {
    if (z > 20.f)  return z;
    if (z < -20.f) return expf(z);
    return log1pf(expf(z));
}

// K1: per-token forward + per-token gradients.
// block = token (b*L+l), 256 threads.
__global__ __launch_bounds__(256) void k_token(
    const float* __restrict__ x,
    const float* __restrict__ W1, const float* __restrict__ b1,
    const float* __restrict__ W2, const float* __restrict__ b2,
    const float* __restrict__ Wq, const float* __restrict__ bq,
    const float* __restrict__ Wk, const float* __restrict__ bk,
    const float* __restrict__ Wv, const float* __restrict__ bv,
    float* __restrict__ qo, float* __restrict__ ko,
    float* __restrict__ X2o, float* __restrict__ gZ1o, float* __restrict__ gZ2o)
{
    __shared__ float xs[Dc], ks[Dc], vs[Dc], X2s[Hc], gZ2s[Dc];
    const int t   = blockIdx.x;     // token index 0..B*L-1
    const int tid = threadIdx.x;

    if (tid < Dc) xs[tid] = x[t * Dc + tid];
    __syncthreads();

    if (tid < Dc) {
        float aq = bq[tid], ak = bk[tid], av = bv[tid];
        const float* wqr = Wq + tid * Dc;
        const float* wkr = Wk + tid * Dc;
        const float* wvr = Wv + tid * Dc;
        for (int j = 0; j < Dc; ++j) {
            float xv = xs[j];
            aq += wqr[j] * xv; ak += wkr[j] * xv; av += wvr[j] * xv;
        }
        qo[t * Dc + tid] = aq;
        ko[t * Dc + tid] = ak;
        ks[tid] = ak; vs[tid] = av;
    }
    __syncthreads();

    // Z1[h] = b1[h] + W1[h,:] . k ; X2 = silu(Z1)
    float z1;
    {
        float a = b1[tid];
        const float* w1r = W1 + tid * Dc;
        for (int j = 0; j < Dc; ++j) a += w1r[j] * ks[j];
        z1 = a;
        float s = siluf(a);
        X2s[tid] = s;
        X2o[t * Hc + tid] = s;
    }
    __syncthreads();

    // Z2[d] = b2[d] + W2[d,:] . X2 ; gZ2 = Z2 - v
    if (tid < Dc) {
        float a = b2[tid];
        const float* w2r = W2 + tid * Hc;
        for (int j = 0; j < Hc; ++j) a += w2r[j] * X2s[j];
        float g = a - vs[tid];
        gZ2s[tid] = g;
        gZ2o[t * Dc + tid] = g;
    }
    __syncthreads();

    // gX2[h] = sum_d gZ2[d]*W2[d,h] ; gZ1 = gX2 * silu_bwd(Z1)
    {
        float a = 0.f;
        for (int d = 0; d < Dc; ++d) a += gZ2s[d] * W2[d * Hc + tid];
        gZ1o[t * Hc + tid] = a * silubwdf(z1);
    }
}

// K2: gates (lr, log_mom, log_wd), inclusive cumsums, composed decay matrix
// Ssc[b,l,m] = S[l,m]*lr[m] (S = wd_cs @ mom_cs), and wd_full = exp(cumsum log_wd).
// block = batch, thread = sequence position.
__global__ __launch_bounds__(256) void k_scan(
    const float* __restrict__ x,
    const float* __restrict__ Wlr, const float* __restrict__ blr,
    const float* __restrict__ Wm,  const float* __restrict__ bm,
    const float* __restrict__ Wwd, const float* __restrict__ bwd,
    float* __restrict__ Ssc, float* __restrict__ wdf)
{
    __shared__ float lrS[Lc], lwS[Lc], clmS[Lc], cwdS[Lc];
    const int b = blockIdx.x;
    const int l = threadIdx.x;

    const float* xr = x + (b * Lc + l) * Dc;
    float dlr = blr[0], dm = bm[0], dw = bwd[0];
    for (int j = 0; j < Dc; ++j) {
        float xv = xr[j];
        dlr += Wlr[j] * xv; dm += Wm[j] * xv; dw += Wwd[j] * xv;
    }
    lrS[l] = softplusf(dlr);
    float lm = -softplusf(-dm);   // log sigmoid
    float lw = -softplusf(-dw);
    lwS[l]  = lw;
    clmS[l] = lm;
    cwdS[l] = lw;
    __syncthreads();

    // inclusive Hillis-Steele scans
    for (int off = 1; off < Lc; off <<= 1) {
        float a = (l >= off) ? clmS[l - off] : 0.f;
        float c = (l >= off) ? cwdS[l - off] : 0.f;
        __syncthreads();
        clmS[l] += a; cwdS[l] += c;
        __syncthreads();
    }
    wdf[b * Lc + l] = expf(cwdS[l]);

    // S[l,m] = wd[l]*S[l-1,m] + exp(clm[l]-clm[m]); thread m scans over l.
    const int m = l;
    const float clm_m = clmS[m];
    const float lrm   = lrS[m];
    float s = 0.f;
    for (int ll = 0; ll < Lc; ++ll) {
        if (ll >= m) s = expf(lwS[ll]) * s + expf(clmS[ll] - clm_m);
        Ssc[(b * Lc + ll) * Lc + m] = s * lrm;   // zero above diagonal
    }
}

// K3/K5: score kernels A[l,m] = Ssc[l,m]*(u[l].w[m] + 1), dot length DIM.
template <int DIM>
__global__ __launch_bounds__(256) void k_score(
    const float* __restrict__ U, const float* __restrict__ W,
    const float* __restrict__ Ssc, float* __restrict__ A)
{
    __shared__ float us[DIM];
    const int t   = blockIdx.x;   // (b*L + l)
    const int b   = t >> 8;
    const int tid = threadIdx.x;  // m
    if (DIM == 128) { if (tid < DIM) us[tid] = U[t * DIM + tid]; }
    else            { us[tid] = U[t * DIM + tid]; }
    __syncthreads();
    const float* wr = W + (b * Lc + tid) * DIM;
    float d = 0.f;
    for (int j = 0; j < DIM; ++j) d += us[j] * wr[j];
    A[t * Lc + tid] = Ssc[t * Lc + tid] * (d + 1.f);
}

// K4: Zq1[l,h] = sum_m A[l,m]*gZ1[m,h] + wd_full[l]*(b1[h] + W1[h,:].q[l]); Xq2 = silu.
__global__ __launch_bounds__(256) void k_zq1(
    const float* __restrict__ A, const float* __restrict__ gZ1,
    const float* __restrict__ q, const float* __restrict__ W1, const float* __restrict__ b1,
    const float* __restrict__ wdf, float* __restrict__ Xq2)
{
    __shared__ float arow[Lc], qs[Dc];
    const int t = blockIdx.x;
    const int b = t >> 8;
    const int tid = threadIdx.x;  // h
    arow[tid] = A[t * Lc + tid];
    if (tid < Dc) qs[tid] = q[t * Dc + tid];
    __syncthreads();
    float acc = 0.f;
    const float* g = gZ1 + b * Lc * Hc + tid;
    for (int m = 0; m < Lc; ++m) acc += arow[m] * g[m * Hc];
    float wq = b1[tid];
    const float* w1r = W1 + tid * Dc;
    for (int j = 0; j < Dc; ++j) wq += w1r[j] * qs[j];
    float z = acc + wdf[t] * wq;
    Xq2[t * Hc + tid] = siluf(z);
}

// K6: out[l,d] = sum_m A[l,m]*gZ2[m,d] + wd_full[l]*(b2[d] + W2[d,:].Xq2[l]).
__global__ __launch_bounds__(128) void k_zq2(
    const float* __restrict__ A, const float* __restrict__ gZ2,
    const float* __restrict__ Xq2, const float* __restrict__ W2, const float* __restrict__ b2,
    const float* __restrict__ wdf, float* __restrict__ out)
{
    __shared__ float arow[Lc], xqs[Hc];
    const int t = blockIdx.x;
    const int b = t >> 8;
    const int tid = threadIdx.x;  // d, 128 threads
    arow[tid]      = A[t * Lc + tid];
    arow[tid + 128] = A[t * Lc + tid + 128];
    xqs[tid]       = Xq2[t * Hc + tid];
    xqs[tid + 128] = Xq2[t * Hc + tid + 128];
    __syncthreads();
    float acc = 0.f;
    const float* g = gZ2 + b * Lc * Dc + tid;
    for (int m = 0; m < Lc; ++m) acc += arow[m] * g[m * Dc];
    float wq = b2[tid];
    const float* w2r = W2 + tid * Hc;
    for (int j = 0; j < Hc; ++j) wq += w2r[j] * xqs[j];
    out[t * Dc + tid] = acc + wdf[t] * wq;
}

extern "C" void kernel_launch(void* const* d_in, const int* in_sizes, int n_in,
                              void* d_out, int out_size, void* d_ws, size_t ws_size,
                              hipStream_t stream)
{
    const float* x   = (const float*)d_in[0];
    const float* W1  = (const float*)d_in[1];
    const float* b1  = (const float*)d_in[2];
    const float* W2  = (const float*)d_in[3];
    const float* b2  = (const float*)d_in[4];
    const float* Wq  = (const float*)d_in[5];
    const float* bq  = (const float*)d_in[6];
    const float* Wk  = (const float*)d_in[7];
    const float* bk  = (const float*)d_in[8];
    const float* Wv  = (const float*)d_in[9];
    const float* bv  = (const float*)d_in[10];
    const float* Wlr = (const float*)d_in[11];
    const float* blr = (const float*)d_in[12];
    const float* Wm  = (const float*)d_in[13];
    const float* bm  = (const float*)d_in[14];
    const float* Wwd = (const float*)d_in[15];
    const float* bwd = (const float*)d_in[16];

    float* ws  = (float*)d_ws;
    float* q   = ws;              // B*L*D   = 65536
    float* kk  = q   + Bc*Lc*Dc;  // 65536
    float* X2  = kk  + Bc*Lc*Dc;  // B*L*H   = 131072
    float* gZ1 = X2  + Bc*Lc*Hc;  // 131072
    float* gZ2 = gZ1 + Bc*Lc*Hc;  // 65536
    float* Ssc = gZ2 + Bc*Lc*Dc;  // B*L*L   = 131072
    float* A   = Ssc + Bc*Lc*Lc;  // 131072 (reused for A1 then A2)
    float* Xq2 = A   + Bc*Lc*Lc;  // 131072
    float* wdf = Xq2 + Bc*Lc*Hc;  // 512
    float* out = (float*)d_out;

    k_token<<<Bc * Lc, 256, 0, stream>>>(x, W1, b1, W2, b2, Wq, bq, Wk, bk, Wv, bv,
                                         q, kk, X2, gZ1, gZ2);
    k_scan<<<Bc, 256, 0, stream>>>(x, Wlr, blr, Wm, bm, Wwd, bwd, Ssc, wdf);
    k_score<Dc><<<Bc * Lc, 256, 0, stream>>>(q, kk, Ssc, A);
    k_zq1<<<Bc * Lc, 256, 0, stream>>>(A, gZ1, q, W1, b1, wdf, Xq2);
    k_score<Hc><<<Bc * Lc, 256, 0, stream>>>(Xq2, X2, Ssc, A);
    k_zq2<<<Bc * Lc, 128, 0, stream>>>(A, gZ2, Xq2, W2, b2, wdf, out);
}

// Round 2
// 214.329 us; speedup vs baseline: 1.0120x; 1.0120x over previous
//
#include <hip/hip_runtime.h>
#include <hip/hip_bf16.h>

// B=2, L=256, D=128, H=256 fast-weight (TTT-style) forward.
// Exact rewrite: sequential momentum/weight-decay scan -> decay-weighted
// attention with composed decay matrix S = wd_cs @ mom_cs via the stable
// O(L^2) recurrence  S[l,m] = wd[l]*S[l-1,m] + exp(clm[l]-clm[m])
// (all exponents <= 0 in the live region).
//
// 3 kernels: k_token (per-token fwd+grads), k_scan (gates + decay matrix),
// k_query (score1 -> Zq1/silu -> score2 -> Zq2, fused per token in LDS).

#define Bc 2
#define Lc 256
#define Dc 128
#define Hc 256

__device__ __forceinline__ float sigf(float z)  { return 1.f / (1.f + expf(-z)); }
__device__ __forceinline__ float siluf(float z) { return z * sigf(z); }
// replicates reference silu_backward exactly: s + sigmoid(z)*(1-s), s=silu(z)
__device__ __forceinline__ float silubwdf(float z) {
    float sg = sigf(z);
    float s  = z * sg;
    return s + sg * (1.f - s);
}
__device__ __forceinline__ float softplusf(float z) {
    if (z > 20.f)  return z;
    if (z < -20.f) return expf(z);
    return log1pf(expf(z));
}
__device__ __forceinline__ float dot4(float4 a, float4 b) {
    return a.x*b.x + a.y*b.y + a.z*b.z + a.w*b.w;
}

// ---------------------------------------------------------------------------
// K1: per-token forward + per-token gradients. block = token, 256 threads.
// ---------------------------------------------------------------------------
__global__ __launch_bounds__(256) void k_token(
    const float* __restrict__ x,
    const float* __restrict__ W1, const float* __restrict__ b1,
    const float* __restrict__ W2, const float* __restrict__ b2,
    const float* __restrict__ Wq, const float* __restrict__ bq,
    const float* __restrict__ Wk, const float* __restrict__ bk,
    const float* __restrict__ Wv, const float* __restrict__ bv,
    float* __restrict__ qo, float* __restrict__ ko,
    float* __restrict__ X2o, float* __restrict__ gZ1o, float* __restrict__ gZ2o)
{
    __shared__ __align__(16) float xs[Dc];
    __shared__ __align__(16) float ks[Dc];
    __shared__ float vs[Dc];
    __shared__ __align__(16) float X2s[Hc];
    __shared__ float gZ2s[Dc];

    const int t   = blockIdx.x;     // token 0..B*L-1
    const int tid = threadIdx.x;

    if (tid < Dc / 4)
        ((float4*)xs)[tid] = ((const float4*)(x + t * Dc))[tid];
    __syncthreads();

    const float4* xs4 = (const float4*)xs;

    // q & v on threads 0..127, k on threads 128..255 (float4 dots)
    if (tid < Dc) {
        const int d = tid;
        float aq = bq[d], av = bv[d];
        const float4* wq4 = (const float4*)(Wq + d * Dc);
        const float4* wv4 = (const float4*)(Wv + d * Dc);
        #pragma unroll 4
        for (int j = 0; j < Dc / 4; ++j) {
            float4 xv = xs4[j];
            aq += dot4(wq4[j], xv);
            av += dot4(wv4[j], xv);
        }
        qo[t * Dc + d] = aq;
        vs[d] = av;
    } else {
        const int d = tid - Dc;
        float ak = bk[d];
        const float4* wk4 = (const float4*)(Wk + d * Dc);
        #pragma unroll 4
        for (int j = 0; j < Dc / 4; ++j) ak += dot4(wk4[j], xs4[j]);
        ko[t * Dc + d] = ak;
        ks[d] = ak;
    }
    __syncthreads();

    // Z1[h] = b1 + W1[h,:].k ; X2 = silu(Z1)   (all 256 threads, h = tid)
    const float4* ks4 = (const float4*)ks;
    float z1;
    {
        float a = b1[tid];
        const float4* w14 = (const float4*)(W1 + tid * Dc);
        #pragma unroll 4
        for (int j = 0; j < Dc / 4; ++j) a += dot4(w14[j], ks4[j]);
        z1 = a;
        float s = siluf(a);
        X2s[tid] = s;
        X2o[t * Hc + tid] = s;
    }
    __syncthreads();

    // Z2[d] = b2 + W2[d,:].X2 ; gZ2 = Z2 - v   (threads 0..127)
    if (tid < Dc) {
        float a = b2[tid];
        const float4* w24 = (const float4*)(W2 + tid * Hc);
        const float4* X24 = (const float4*)X2s;
        #pragma unroll 4
        for (int j = 0; j < Hc / 4; ++j) a += dot4(w24[j], X24[j]);
        float g = a - vs[tid];
        gZ2s[tid] = g;
        gZ2o[t * Dc + tid] = g;
    }
    __syncthreads();

    // gX2[h] = sum_d gZ2[d]*W2[d,h] (coalesced column read) ; gZ1 = gX2*silu'
    {
        float a = 0.f;
        for (int d = 0; d < Dc; ++d) a += gZ2s[d] * W2[d * Hc + tid];
        gZ1o[t * Hc + tid] = a * silubwdf(z1);
    }
}

// ---------------------------------------------------------------------------
// K2: gates, cumsums, composed decay matrix Ssc[l,m] = S[l,m]*lr[m],
// wd_full = exp(cumsum log_wd).  block = batch, thread = position.
// ---------------------------------------------------------------------------
__global__ __launch_bounds__(256) void k_scan(
    const float* __restrict__ x,
    const float* __restrict__ Wlr, const float* __restrict__ blr,
    const float* __restrict__ Wm,  const float* __restrict__ bm,
    const float* __restrict__ Wwd, const float* __restrict__ bwd,
    float* __restrict__ Ssc, float* __restrict__ wdf)
{
    __shared__ float lrS[Lc], lwS[Lc], ewdS[Lc], clmS[Lc], cwdS[Lc];
    const int b = blockIdx.x;
    const int l = threadIdx.x;

    // gate pre-activations (float4 dots; W* pointers are thread-uniform)
    const float4* xr4 = (const float4*)(x + (b * Lc + l) * Dc);
    const float4* wl4 = (const float4*)Wlr;
    const float4* wm4 = (const float4*)Wm;
    const float4* ww4 = (const float4*)Wwd;
    float dlr = blr[0], dm = bm[0], dw = bwd[0];
    #pragma unroll 4
    for (int j = 0; j < Dc / 4; ++j) {
        float4 xv = xr4[j];
        dlr += dot4(wl4[j], xv);
        dm  += dot4(wm4[j], xv);
        dw  += dot4(ww4[j], xv);
    }
    lrS[l] = softplusf(dlr);
    float lm = -softplusf(-dm);   // log sigmoid
    float lw = -softplusf(-dw);
    lwS[l]  = lw;
    clmS[l] = lm;
    cwdS[l] = lw;
    __syncthreads();

    // inclusive Hillis-Steele scans
    for (int off = 1; off < Lc; off <<= 1) {
        float a = (l >= off) ? clmS[l - off] : 0.f;
        float c = (l >= off) ? cwdS[l - off] : 0.f;
        __syncthreads();
        clmS[l] += a; cwdS[l] += c;
        __syncthreads();
    }
    wdf[b * Lc + l] = expf(cwdS[l]);
    ewdS[l] = __expf(lwS[l]);     // per-row decay factor table
    __syncthreads();

    // S[l,m] = ewd[l]*S[l-1,m] + exp(clm[l]-clm[m]); thread m scans over l.
    const int   m     = l;
    const float clm_m = clmS[m];
    const float lrm   = lrS[m];
    float* outp = Ssc + (b * Lc) * Lc + m;
    float s = 0.f;
    for (int ll = 0; ll < Lc; ++ll) {
        float e2 = __expf(clmS[ll] - clm_m);          // valid only ll>=m
        s = (ll >= m) ? (ewdS[ll] * s + e2) : 0.f;
        outp[ll * Lc] = s * lrm;                      // zero above diagonal
    }
}

// ---------------------------------------------------------------------------
// K3: fused query: score1 -> Zq1 -> silu -> score2 -> Zq2.
// block = token, 256 threads; all intermediates in LDS.
// ---------------------------------------------------------------------------
__global__ __launch_bounds__(256) void k_query(
    const float* __restrict__ q,   const float* __restrict__ kk,
    const float* __restrict__ X2,  const float* __restrict__ gZ1,
    const float* __restrict__ gZ2, const float* __restrict__ Ssc,
    const float* __restrict__ wdf,
    const float* __restrict__ W1, const float* __restrict__ b1,
    const float* __restrict__ W2, const float* __restrict__ b2,
    float* __restrict__ out)
{
    __shared__ float ss[Lc], arow[Lc], pm[256], pw[256];
    __shared__ __align__(16) float qs[Dc];
    __shared__ __align__(16) float xq2s[Hc];

    const int t   = blockIdx.x;
    const int b   = t >> 8;
    const int tid = threadIdx.x;

    ss[tid] = Ssc[t * Lc + tid];
    if (tid < Dc / 4)
        ((float4*)qs)[tid] = ((const float4*)(q + t * Dc))[tid];
    __syncthreads();

    const float wdf_t = wdf[t];
    const float4* qs4 = (const float4*)qs;

    // --- score1: arow[m] = ss[m]*(q[t].k[m] + 1) ---
    {
        const int m = tid;
        const float4* kr4 = (const float4*)(kk + (b * Lc + m) * Dc);
        float d = 0.f;
        #pragma unroll 4
        for (int j = 0; j < Dc / 4; ++j) d += dot4(kr4[j], qs4[j]);
        arow[m] = ss[m] * (d + 1.f);
    }
    __syncthreads();

    // --- Zq1[h] = sum_m arow[m]*gZ1[m,h] + wdf*(b1[h] + W1[h,:].q) ; silu ---
    {
        const int h = tid;
        float acc = 0.f;
        const float* g = gZ1 + b * Lc * Hc + h;
        for (int m = 0; m < Lc; ++m) acc += arow[m] * g[m * Hc];
        float wq = b1[h];
        const float4* w14 = (const float4*)(W1 + h * Dc);
        #pragma unroll 4
        for (int j = 0; j < Dc / 4; ++j) wq += dot4(w14[j], qs4[j]);
        xq2s[h] = siluf(acc + wdf_t * wq);
    }
    __syncthreads();

    // --- score2: arow[m] = ss[m]*(Xq2[t].X2[m] + 1) ---
    {
        const int m = tid;
        const float4* xr4 = (const float4*)(X2 + (b * Lc + m) * Hc);
        const float4* u4  = (const float4*)xq2s;
        float d = 0.f;
        #pragma unroll 4
        for (int j = 0; j < Hc / 4; ++j) d += dot4(xr4[j], u4[j]);
        arow[m] = ss[m] * (d + 1.f);
    }
    __syncthreads();

    // --- Zq2[d] = sum_m arow[m]*gZ2[m,d] + wdf*(b2[d] + W2[d,:].Xq2) ---
    {
        const int d    = tid & 127;
        const int half = tid >> 7;
        float accm = 0.f;
        const float* g = gZ2 + b * Lc * Dc + d;
        const int m0 = half * 128;
        for (int m = m0; m < m0 + 128; ++m) accm += arow[m] * g[m * Dc];
        float accw = 0.f;
        const float4* w24 = (const float4*)(W2 + d * Hc) + half * 32;
        const float4* u4  = (const float4*)xq2s + half * 32;
        #pragma unroll 4
        for (int j = 0; j < 32; ++j) accw += dot4(w24[j], u4[j]);
        pm[tid] = accm; pw[tid] = accw;
    }
    __syncthreads();

    if (tid < Dc) {
        float z = (pm[tid] + pm[tid + 128])
                + wdf_t * (b2[tid] + pw[tid] + pw[tid + 128]);
        out[t * Dc + tid] = z;
    }
}

// ---------------------------------------------------------------------------
extern "C" void kernel_launch(void* const* d_in, const int* in_sizes, int n_in,
                              void* d_out, int out_size, void* d_ws, size_t ws_size,
                              hipStream_t stream)
{
    const float* x   = (const float*)d_in[0];
    const float* W1  = (const float*)d_in[1];
    const float* b1  = (const float*)d_in[2];
    const float* W2  = (const float*)d_in[3];
    const float* b2  = (const float*)d_in[4];
    const float* Wq  = (const float*)d_in[5];
    const float* bq  = (const float*)d_in[6];
    const float* Wk  = (const float*)d_in[7];
    const float* bk  = (const float*)d_in[8];
    const float* Wv  = (const float*)d_in[9];
    const float* bv  = (const float*)d_in[10];
    const float* Wlr = (const float*)d_in[11];
    const float* blr = (const float*)d_in[12];
    const float* Wm  = (const float*)d_in[13];
    const float* bm  = (const float*)d_in[14];
    const float* Wwd = (const float*)d_in[15];
    const float* bwd = (const float*)d_in[16];

    float* ws  = (float*)d_ws;
    float* q   = ws;              // B*L*D = 65536
    float* kk  = q   + Bc*Lc*Dc;  // 65536
    float* X2  = kk  + Bc*Lc*Dc;  // B*L*H = 131072
    float* gZ1 = X2  + Bc*Lc*Hc;  // 131072
    float* gZ2 = gZ1 + Bc*Lc*Hc;  // 65536
    float* Ssc = gZ2 + Bc*Lc*Dc;  // B*L*L = 131072
    float* wdf = Ssc + Bc*Lc*Lc;  // 512
    float* out = (float*)d_out;

    k_token<<<Bc * Lc, 256, 0, stream>>>(x, W1, b1, W2, b2, Wq, bq, Wk, bk, Wv, bv,
                                         q, kk, X2, gZ1, gZ2);
    k_scan<<<Bc, 256, 0, stream>>>(x, Wlr, blr, Wm, bm, Wwd, bwd, Ssc, wdf);
    k_query<<<Bc * Lc, 256, 0, stream>>>(q, kk, X2, gZ1, gZ2, Ssc, wdf,
                                         W1, b1, W2, b2, out);
}

// Round 3
// 169.530 us; speedup vs baseline: 1.2794x; 1.2643x over previous
//
#include <hip/hip_runtime.h>
#include <hip/hip_bf16.h>

// B=2, L=256, D=128, H=256 fast-weight (TTT-style) forward.
// Exact rewrite: sequential momentum/weight-decay scan -> decay-weighted
// attention with composed decay matrix S = wd_cs @ mom_cs via the stable
// O(L^2) recurrence (all exponents <= 0 in the live region).
//
// v3: coalescing-first restructure.
//  - k_prep : transpose Wq,Wk,Wv,W1,W2 once (32x32 LDS tiles).
//  - k_token: 4 tokens/block; all dots are "LDS broadcast x coalesced row".
//             Emits q, KT[d][m], X2T[h][m], z1q (=b1+W1.q), gZ1, gZ2.
//  - k_scan : gates + cumsums + decay-matrix recurrence (unchanged).
//  - k_query: 4 tokens/block fused score1->Zq1->silu->score2->Zq2.

#define Bc 2
#define Lc 256
#define Dc 128
#define Hc 256
#define Tt 4   // tokens per block

__device__ __forceinline__ float sigf(float z)  { return 1.f / (1.f + expf(-z)); }
__device__ __forceinline__ float siluf(float z) { return z * sigf(z); }
// replicates reference silu_backward exactly: s + sigmoid(z)*(1-s), s=silu(z)
__device__ __forceinline__ float silubwdf(float z) {
    float sg = sigf(z);
    float s  = z * sg;
    return s + sg * (1.f - s);
}
__device__ __forceinline__ float softplusf(float z) {
    if (z > 20.f)  return z;
    if (z < -20.f) return expf(z);
    return log1pf(expf(z));
}
__device__ __forceinline__ float dot4(float4 a, float4 b) {
    return a.x*b.x + a.y*b.y + a.z*b.z + a.w*b.w;
}

// ---------------------------------------------------------------------------
// K0: weight transposes. 112 blocks of 256 threads, 32x32 LDS tiles.
// ---------------------------------------------------------------------------
__global__ __launch_bounds__(256) void k_prep(
    const float* __restrict__ Wq, const float* __restrict__ Wk,
    const float* __restrict__ Wv, const float* __restrict__ W1,
    const float* __restrict__ W2,
    float* __restrict__ WqT, float* __restrict__ WkT, float* __restrict__ WvT,
    float* __restrict__ W1T, float* __restrict__ W2T)
{
    __shared__ float tile[32][33];
    const int bb = blockIdx.x;
    const float* src; float* dst; int R, C, t0;
    if      (bb < 16) { src = Wq; dst = WqT; R = 128; C = 128; t0 = bb;      }
    else if (bb < 32) { src = Wk; dst = WkT; R = 128; C = 128; t0 = bb - 16; }
    else if (bb < 48) { src = Wv; dst = WvT; R = 128; C = 128; t0 = bb - 32; }
    else if (bb < 80) { src = W1; dst = W1T; R = 256; C = 128; t0 = bb - 48; }
    else              { src = W2; dst = W2T; R = 128; C = 256; t0 = bb - 80; }
    const int tilesC = C >> 5;
    const int tr = t0 / tilesC, tc = t0 % tilesC;
    const int i = threadIdx.x >> 5, j = threadIdx.x & 31;
    #pragma unroll
    for (int p = 0; p < 4; ++p)
        tile[i + p*8][j] = src[(tr*32 + i + p*8) * C + tc*32 + j];
    __syncthreads();
    #pragma unroll
    for (int p = 0; p < 4; ++p)
        dst[(tc*32 + i + p*8) * R + tr*32 + j] = tile[j][i + p*8];
}

// ---------------------------------------------------------------------------
// K1: per-token forward + gradients. 128 blocks x 256 threads, 4 tokens/block.
// ---------------------------------------------------------------------------
__global__ __launch_bounds__(256) void k_token(
    const float* __restrict__ x,
    const float* __restrict__ b1v, const float* __restrict__ b2v,
    const float* __restrict__ bq,  const float* __restrict__ bk,
    const float* __restrict__ bv,
    const float* __restrict__ WqT, const float* __restrict__ WkT,
    const float* __restrict__ WvT, const float* __restrict__ W1T,
    const float* __restrict__ W2T, const float* __restrict__ W2,
    float* __restrict__ qo, float* __restrict__ KT, float* __restrict__ X2T,
    float* __restrict__ z1q, float* __restrict__ gZ1, float* __restrict__ gZ2)
{
    __shared__ __align__(16) float xs[Tt][Dc], qs[Tt][Dc], ks[Tt][Dc];
    __shared__ __align__(16) float vs[Tt][Dc], X2s[Tt][Hc];
    __shared__ __align__(16) float pz[2][Tt][Dc], gZ2s[Tt][Dc];

    const int t0  = blockIdx.x * Tt;      // global token base
    const int b   = t0 >> 8;
    const int l0  = t0 & 255;
    const int tid = threadIdx.x;

    if (tid < Tt * Dc / 4)
        ((float4*)&xs[0][0])[tid] = ((const float4*)(x + t0 * Dc))[tid];
    __syncthreads();

    // --- q & v (threads 0..127) | k (threads 128..255) ---
    if (tid < 128) {
        const int c = tid;
        float aq[Tt], av[Tt];
        #pragma unroll
        for (int t = 0; t < Tt; ++t) { aq[t] = bq[c]; av[t] = bv[c]; }
        for (int j = 0; j < Dc; j += 4) {
            float wq0 = WqT[(j+0)*Dc + c], wq1 = WqT[(j+1)*Dc + c];
            float wq2 = WqT[(j+2)*Dc + c], wq3 = WqT[(j+3)*Dc + c];
            float wv0 = WvT[(j+0)*Dc + c], wv1 = WvT[(j+1)*Dc + c];
            float wv2 = WvT[(j+2)*Dc + c], wv3 = WvT[(j+3)*Dc + c];
            #pragma unroll
            for (int t = 0; t < Tt; ++t) {
                float4 xv = *(const float4*)&xs[t][j];
                aq[t] += xv.x*wq0 + xv.y*wq1 + xv.z*wq2 + xv.w*wq3;
                av[t] += xv.x*wv0 + xv.y*wv1 + xv.z*wv2 + xv.w*wv3;
            }
        }
        #pragma unroll
        for (int t = 0; t < Tt; ++t) {
            qs[t][c] = aq[t]; vs[t][c] = av[t];
            qo[(t0 + t) * Dc + c] = aq[t];
        }
    } else {
        const int c = tid - 128;
        float ak[Tt];
        #pragma unroll
        for (int t = 0; t < Tt; ++t) ak[t] = bk[c];
        for (int j = 0; j < Dc; j += 4) {
            float wk0 = WkT[(j+0)*Dc + c], wk1 = WkT[(j+1)*Dc + c];
            float wk2 = WkT[(j+2)*Dc + c], wk3 = WkT[(j+3)*Dc + c];
            #pragma unroll
            for (int t = 0; t < Tt; ++t) {
                float4 xv = *(const float4*)&xs[t][j];
                ak[t] += xv.x*wk0 + xv.y*wk1 + xv.z*wk2 + xv.w*wk3;
            }
        }
        #pragma unroll
        for (int t = 0; t < Tt; ++t) ks[t][c] = ak[t];
        float4 kv = make_float4(ak[0], ak[1], ak[2], ak[3]);
        *(float4*)(KT + b*Dc*Lc + c*Lc + l0) = kv;
    }
    __syncthreads();

    // --- Z1 (from k) and z1q (=b1+W1.q) on thread h; X2 = silu(Z1) ---
    float z1r[Tt];
    {
        const int h = tid;
        const float bb1 = b1v[h];
        float a[Tt], aq[Tt];
        #pragma unroll
        for (int t = 0; t < Tt; ++t) { a[t] = bb1; aq[t] = bb1; }
        for (int d = 0; d < Dc; d += 4) {
            float w0 = W1T[(d+0)*Hc + h], w1 = W1T[(d+1)*Hc + h];
            float w2 = W1T[(d+2)*Hc + h], w3 = W1T[(d+3)*Hc + h];
            #pragma unroll
            for (int t = 0; t < Tt; ++t) {
                float4 kv = *(const float4*)&ks[t][d];
                float4 qv = *(const float4*)&qs[t][d];
                a[t]  += kv.x*w0 + kv.y*w1 + kv.z*w2 + kv.w*w3;
                aq[t] += qv.x*w0 + qv.y*w1 + qv.z*w2 + qv.w*w3;
            }
        }
        float s[Tt];
        #pragma unroll
        for (int t = 0; t < Tt; ++t) {
            z1r[t] = a[t];
            s[t] = siluf(a[t]);
            X2s[t][h] = s[t];
            z1q[(t0 + t) * Hc + h] = aq[t];
        }
        *(float4*)(X2T + b*Hc*Lc + h*Lc + l0) = make_float4(s[0], s[1], s[2], s[3]);
    }
    __syncthreads();

    // --- Z2 halves: thread (hf, d) ---
    {
        const int d = tid & 127, hf = tid >> 7;
        float a[Tt] = {0.f, 0.f, 0.f, 0.f};
        const int h0 = hf * 128;
        for (int hh = 0; hh < 128; hh += 4) {
            const int h = h0 + hh;
            float w0 = W2T[(h+0)*Dc + d], w1 = W2T[(h+1)*Dc + d];
            float w2 = W2T[(h+2)*Dc + d], w3 = W2T[(h+3)*Dc + d];
            #pragma unroll
            for (int t = 0; t < Tt; ++t) {
                float4 xv = *(const float4*)&X2s[t][h];
                a[t] += xv.x*w0 + xv.y*w1 + xv.z*w2 + xv.w*w3;
            }
        }
        #pragma unroll
        for (int t = 0; t < Tt; ++t) pz[hf][t][d] = a[t];
    }
    __syncthreads();
    if (tid < 128) {
        const int d = tid;
        #pragma unroll
        for (int t = 0; t < Tt; ++t) {
            float g = pz[0][t][d] + pz[1][t][d] + b2v[d] - vs[t][d];
            gZ2s[t][d] = g;
            gZ2[(t0 + t) * Dc + d] = g;
        }
    }
    __syncthreads();

    // --- gX2 via W2 columns (coalesced); gZ1 = gX2 * silu_bwd(Z1) ---
    {
        const int h = tid;
        float a[Tt] = {0.f, 0.f, 0.f, 0.f};
        for (int d = 0; d < Dc; d += 4) {
            float w0 = W2[(d+0)*Hc + h], w1 = W2[(d+1)*Hc + h];
            float w2 = W2[(d+2)*Hc + h], w3 = W2[(d+3)*Hc + h];
            #pragma unroll
            for (int t = 0; t < Tt; ++t) {
                float4 gv = *(const float4*)&gZ2s[t][d];
                a[t] += gv.x*w0 + gv.y*w1 + gv.z*w2 + gv.w*w3;
            }
        }
        #pragma unroll
        for (int t = 0; t < Tt; ++t)
            gZ1[(t0 + t) * Hc + h] = a[t] * silubwdf(z1r[t]);
    }
}

// ---------------------------------------------------------------------------
// K2: gates, cumsums, composed decay matrix Ssc[l,m] = S[l,m]*lr[m],
// wd_full = exp(cumsum log_wd).  block = batch, thread = position.
// ---------------------------------------------------------------------------
__global__ __launch_bounds__(256) void k_scan(
    const float* __restrict__ x,
    const float* __restrict__ Wlr, const float* __restrict__ blr,
    const float* __restrict__ Wm,  const float* __restrict__ bm,
    const float* __restrict__ Wwd, const float* __restrict__ bwd,
    float* __restrict__ Ssc, float* __restrict__ wdf)
{
    __shared__ float lrS[Lc], lwS[Lc], ewdS[Lc], clmS[Lc], cwdS[Lc];
    const int b = blockIdx.x;
    const int l = threadIdx.x;

    const float4* xr4 = (const float4*)(x + (b * Lc + l) * Dc);
    const float4* wl4 = (const float4*)Wlr;
    const float4* wm4 = (const float4*)Wm;
    const float4* ww4 = (const float4*)Wwd;
    float dlr = blr[0], dm = bm[0], dw = bwd[0];
    #pragma unroll 4
    for (int j = 0; j < Dc / 4; ++j) {
        float4 xv = xr4[j];
        dlr += dot4(wl4[j], xv);
        dm  += dot4(wm4[j], xv);
        dw  += dot4(ww4[j], xv);
    }
    lrS[l] = softplusf(dlr);
    float lm = -softplusf(-dm);   // log sigmoid
    float lw = -softplusf(-dw);
    lwS[l]  = lw;
    clmS[l] = lm;
    cwdS[l] = lw;
    __syncthreads();

    for (int off = 1; off < Lc; off <<= 1) {
        float a = (l >= off) ? clmS[l - off] : 0.f;
        float c = (l >= off) ? cwdS[l - off] : 0.f;
        __syncthreads();
        clmS[l] += a; cwdS[l] += c;
        __syncthreads();
    }
    wdf[b * Lc + l] = expf(cwdS[l]);
    ewdS[l] = __expf(lwS[l]);
    __syncthreads();

    const int   m     = l;
    const float clm_m = clmS[m];
    const float lrm   = lrS[m];
    float* outp = Ssc + (b * Lc) * Lc + m;
    float s = 0.f;
    for (int ll = 0; ll < Lc; ++ll) {
        float e2 = __expf(clmS[ll] - clm_m);
        s = (ll >= m) ? (ewdS[ll] * s + e2) : 0.f;
        outp[ll * Lc] = s * lrm;
    }
}

// ---------------------------------------------------------------------------
// K3: fused query. 128 blocks x 256 threads, 4 tokens/block.
// ---------------------------------------------------------------------------
__global__ __launch_bounds__(256) void k_query(
    const float* __restrict__ qo,  const float* __restrict__ KT,
    const float* __restrict__ X2T, const float* __restrict__ gZ1,
    const float* __restrict__ gZ2, const float* __restrict__ z1q,
    const float* __restrict__ Ssc, const float* __restrict__ wdf,
    const float* __restrict__ W2T, const float* __restrict__ b2v,
    float* __restrict__ out)
{
    __shared__ __align__(16) float qs[Tt][Dc];
    __shared__ __align__(16) float ssS[Tt][Lc], arow[Tt][Lc];
    __shared__ __align__(16) float xq2s[Tt][Hc];
    __shared__ __align__(16) float pm[2][Tt][Dc], pw[2][Tt][Dc];

    const int t0  = blockIdx.x * Tt;
    const int b   = t0 >> 8;
    const int tid = threadIdx.x;

    if (tid < Tt * Dc / 4)
        ((float4*)&qs[0][0])[tid] = ((const float4*)(qo + t0 * Dc))[tid];
    float wdfv[Tt];
    #pragma unroll
    for (int t = 0; t < Tt; ++t) wdfv[t] = wdf[t0 + t];
    __syncthreads();

    // --- score1: arow[t][m] = Ssc[t][m]*(q[t].k[m] + 1) ---
    {
        const int m = tid;
        const float* ktb = KT + b * Dc * Lc + m;
        float acc[Tt] = {0.f, 0.f, 0.f, 0.f};
        for (int d = 0; d < Dc; d += 4) {
            float k0 = ktb[(d+0)*Lc], k1 = ktb[(d+1)*Lc];
            float k2 = ktb[(d+2)*Lc], k3 = ktb[(d+3)*Lc];
            #pragma unroll
            for (int t = 0; t < Tt; ++t) {
                float4 qv = *(const float4*)&qs[t][d];
                acc[t] += qv.x*k0 + qv.y*k1 + qv.z*k2 + qv.w*k3;
            }
        }
        #pragma unroll
        for (int t = 0; t < Tt; ++t) {
            float s = Ssc[(t0 + t) * Lc + m];
            ssS[t][m]  = s;
            arow[t][m] = s * (acc[t] + 1.f);
        }
    }
    __syncthreads();

    // --- Zq1[t][h] = sum_m arow*gZ1 + wdf*z1q ; silu ---
    {
        const int h = tid;
        const float* g = gZ1 + b * Lc * Hc + h;
        float acc[Tt] = {0.f, 0.f, 0.f, 0.f};
        for (int m = 0; m < Lc; m += 4) {
            float g0 = g[(m+0)*Hc], g1 = g[(m+1)*Hc];
            float g2 = g[(m+2)*Hc], g3 = g[(m+3)*Hc];
            #pragma unroll
            for (int t = 0; t < Tt; ++t) {
                float4 av = *(const float4*)&arow[t][m];
                acc[t] += av.x*g0 + av.y*g1 + av.z*g2 + av.w*g3;
            }
        }
        #pragma unroll
        for (int t = 0; t < Tt; ++t) {
            float z = acc[t] + wdfv[t] * z1q[(t0 + t) * Hc + h];
            xq2s[t][h] = siluf(z);
        }
    }
    __syncthreads();

    // --- score2: arow[t][m] = Ssc[t][m]*(Xq2[t].X2[m] + 1) ---
    {
        const int m = tid;
        const float* xtb = X2T + b * Hc * Lc + m;
        float acc[Tt] = {0.f, 0.f, 0.f, 0.f};
        for (int h = 0; h < Hc; h += 4) {
            float x0 = xtb[(h+0)*Lc], x1 = xtb[(h+1)*Lc];
            float x2 = xtb[(h+2)*Lc], x3 = xtb[(h+3)*Lc];
            #pragma unroll
            for (int t = 0; t < Tt; ++t) {
                float4 xv = *(const float4*)&xq2s[t][h];
                acc[t] += xv.x*x0 + xv.y*x1 + xv.z*x2 + xv.w*x3;
            }
        }
        __syncthreads();   // arow from Zq1 stage fully consumed before overwrite
        #pragma unroll
        for (int t = 0; t < Tt; ++t)
            arow[t][m] = ssS[t][m] * (acc[t] + 1.f);
    }
    __syncthreads();

    // --- Zq2 halves: thread (hf, d) over its half of m / h ---
    {
        const int d = tid & 127, hf = tid >> 7;
        const int m0 = hf * 128;
        float am[Tt] = {0.f, 0.f, 0.f, 0.f};
        float aw[Tt] = {0.f, 0.f, 0.f, 0.f};
        const float* g = gZ2 + (b * Lc + m0) * Dc + d;
        for (int mm = 0; mm < 128; mm += 4) {
            const int m = m0 + mm;
            float g0 = g[(mm+0)*Dc], g1 = g[(mm+1)*Dc];
            float g2 = g[(mm+2)*Dc], g3 = g[(mm+3)*Dc];
            #pragma unroll
            for (int t = 0; t < Tt; ++t) {
                float4 av = *(const float4*)&arow[t][m];
                am[t] += av.x*g0 + av.y*g1 + av.z*g2 + av.w*g3;
            }
        }
        for (int hh = 0; hh < 128; hh += 4) {
            const int h = m0 + hh;
            float w0 = W2T[(h+0)*Dc + d], w1 = W2T[(h+1)*Dc + d];
            float w2 = W2T[(h+2)*Dc + d], w3 = W2T[(h+3)*Dc + d];
            #pragma unroll
            for (int t = 0; t < Tt; ++t) {
                float4 xv = *(const float4*)&xq2s[t][h];
                aw[t] += xv.x*w0 + xv.y*w1 + xv.z*w2 + xv.w*w3;
            }
        }
        #pragma unroll
        for (int t = 0; t < Tt; ++t) { pm[hf][t][d] = am[t]; pw[hf][t][d] = aw[t]; }
    }
    __syncthreads();
    if (tid < 128) {
        const int d = tid;
        #pragma unroll
        for (int t = 0; t < Tt; ++t)
            out[(t0 + t) * Dc + d] = (pm[0][t][d] + pm[1][t][d])
                + wdfv[t] * (b2v[d] + pw[0][t][d] + pw[1][t][d]);
    }
}

// ---------------------------------------------------------------------------
extern "C" void kernel_launch(void* const* d_in, const int* in_sizes, int n_in,
                              void* d_out, int out_size, void* d_ws, size_t ws_size,
                              hipStream_t stream)
{
    const float* x   = (const float*)d_in[0];
    const float* W1  = (const float*)d_in[1];
    const float* b1  = (const float*)d_in[2];
    const float* W2  = (const float*)d_in[3];
    const float* b2  = (const float*)d_in[4];
    const float* Wq  = (const float*)d_in[5];
    const float* bq  = (const float*)d_in[6];
    const float* Wk  = (const float*)d_in[7];
    const float* bk  = (const float*)d_in[8];
    const float* Wv  = (const float*)d_in[9];
    const float* bv  = (const float*)d_in[10];
    const float* Wlr = (const float*)d_in[11];
    const float* blr = (const float*)d_in[12];
    const float* Wm  = (const float*)d_in[13];
    const float* bm  = (const float*)d_in[14];
    const float* Wwd = (const float*)d_in[15];
    const float* bwd = (const float*)d_in[16];

    float* ws  = (float*)d_ws;
    float* q   = ws;               // B*L*D = 65536
    float* KT  = q   + Bc*Lc*Dc;   // B*D*L = 65536
    float* X2T = KT  + Bc*Dc*Lc;   // B*H*L = 131072
    float* gZ1 = X2T + Bc*Hc*Lc;   // B*L*H = 131072
    float* gZ2 = gZ1 + Bc*Lc*Hc;   // B*L*D = 65536
    float* z1q = gZ2 + Bc*Lc*Dc;   // B*L*H = 131072
    float* Ssc = z1q + Bc*Lc*Hc;   // B*L*L = 131072
    float* wdf = Ssc + Bc*Lc*Lc;   // 512
    float* WqT = wdf + Bc*Lc;      // 16384
    float* WkT = WqT + Dc*Dc;      // 16384
    float* WvT = WkT + Dc*Dc;      // 16384
    float* W1T = WvT + Dc*Dc;      // D*H = 32768
    float* W2T = W1T + Dc*Hc;      // H*D = 32768
    float* out = (float*)d_out;

    k_prep<<<112, 256, 0, stream>>>(Wq, Wk, Wv, W1, W2, WqT, WkT, WvT, W1T, W2T);
    k_token<<<Bc*Lc/Tt, 256, 0, stream>>>(x, b1, b2, bq, bk, bv,
                                          WqT, WkT, WvT, W1T, W2T, W2,
                                          q, KT, X2T, z1q, gZ1, gZ2);
    k_scan<<<Bc, 256, 0, stream>>>(x, Wlr, blr, Wm, bm, Wwd, bwd, Ssc, wdf);
    k_query<<<Bc*Lc/Tt, 256, 0, stream>>>(q, KT, X2T, gZ1, gZ2, z1q, Ssc, wdf,
                                          W2T, b2, out);
}

// Round 4
// 164.717 us; speedup vs baseline: 1.3168x; 1.0292x over previous
//
#include <hip/hip_runtime.h>
#include <hip/hip_bf16.h>

// B=2, L=256, D=128, H=256 fast-weight (TTT-style) forward.
// Exact rewrite: sequential momentum/weight-decay scan -> decay-weighted
// attention with composed decay matrix S = wd_cs @ mom_cs via the stable
// O(L^2) recurrence (all exponents <= 0 in the live region).
//
// v4: every streamed operand uses an interleaved-by-4 layout arr[g][lane][4]
// so inner loops are single coalesced float4 loads (1 KB/wave/instr).
//  - k_pre  : blocks 0..143 interleave Wq,Wk,Wv,W1,W2 (5 variants);
//             blocks 144..145 run the gate/decay-matrix scan.
//  - k_token: 4 tokens/block; emits q, KT4, X2T4, z1q, GZ1q, GZ2q.
//  - k_query: 4 tokens/block fused score1->Zq1->silu->score2->Zq2.

#define Bc 2
#define Lc 256
#define Dc 128
#define Hc 256
#define Tt 4

__device__ __forceinline__ float sigf(float z)  { return 1.f / (1.f + expf(-z)); }
__device__ __forceinline__ float siluf(float z) { return z * sigf(z); }
// replicates reference silu_backward exactly: s + sigmoid(z)*(1-s), s=silu(z)
__device__ __forceinline__ float silubwdf(float z) {
    float sg = sigf(z);
    float s  = z * sg;
    return s + sg * (1.f - s);
}
__device__ __forceinline__ float softplusf(float z) {
    if (z > 20.f)  return z;
    if (z < -20.f) return expf(z);
    return log1pf(expf(z));
}
__device__ __forceinline__ float dot4(float4 a, float4 b) {
    return a.x*b.x + a.y*b.y + a.z*b.z + a.w*b.w;
}

// ---------------------------------------------------------------------------
// K0: blocks 0..143 = weight interleaves; blocks 144..145 = gate scan.
// Type A: out[g*M + r] = {in[r][4g..4g+3]}  (float4 row-chunk gather)
// Type B: W2c4[g*256 + c] = {W2[4g+j][c]}   (column gather)
// ---------------------------------------------------------------------------
__global__ __launch_bounds__(256) void k_pre(
    const float* __restrict__ Wq, const float* __restrict__ Wk,
    const float* __restrict__ Wv, const float* __restrict__ W1,
    const float* __restrict__ W2,
    float4* __restrict__ Wq4, float4* __restrict__ Wk4, float4* __restrict__ Wv4,
    float4* __restrict__ W14, float4* __restrict__ W2q4, float4* __restrict__ W2c4,
    const float* __restrict__ x,
    const float* __restrict__ Wlr, const float* __restrict__ blr,
    const float* __restrict__ Wm,  const float* __restrict__ bm,
    const float* __restrict__ Wwd, const float* __restrict__ bwd,
    float* __restrict__ Ssc, float* __restrict__ wdf)
{
    const int bb = blockIdx.x;
    if (bb < 144) {
        if (bb < 112) {
            const float* in; float4* out; int M, N, base;
            if      (bb < 16) { in = Wq; out = Wq4;  M = 128; N = 128; base = 0;  }
            else if (bb < 32) { in = Wk; out = Wk4;  M = 128; N = 128; base = 16; }
            else if (bb < 48) { in = Wv; out = Wv4;  M = 128; N = 128; base = 32; }
            else if (bb < 80) { in = W1; out = W14;  M = 256; N = 128; base = 48; }
            else              { in = W2; out = W2q4; M = 128; N = 256; base = 80; }
            const int o = (bb - base) * 256 + threadIdx.x;
            const int r = o % M, g = o / M;
            out[o] = *(const float4*)(in + r * N + 4 * g);
        } else {
            const int o = (bb - 112) * 256 + threadIdx.x;   // 0..8191
            const int c = o & 255, g = o >> 8;
            W2c4[o] = make_float4(W2[(4*g+0)*Hc + c], W2[(4*g+1)*Hc + c],
                                  W2[(4*g+2)*Hc + c], W2[(4*g+3)*Hc + c]);
        }
        return;
    }

    // ---- gate scan (2 blocks) ----
    __shared__ float lrS[Lc], lwS[Lc], ewdS[Lc], clmS[Lc], cwdS[Lc];
    const int b = bb - 144;
    const int l = threadIdx.x;

    const float4* xr4 = (const float4*)(x + (b * Lc + l) * Dc);
    const float4* wl4 = (const float4*)Wlr;
    const float4* wm4 = (const float4*)Wm;
    const float4* ww4 = (const float4*)Wwd;
    float dlr = blr[0], dm = bm[0], dw = bwd[0];
    #pragma unroll 4
    for (int j = 0; j < Dc / 4; ++j) {
        float4 xv = xr4[j];
        dlr += dot4(wl4[j], xv);
        dm  += dot4(wm4[j], xv);
        dw  += dot4(ww4[j], xv);
    }
    lrS[l] = softplusf(dlr);
    float lm = -softplusf(-dm);   // log sigmoid
    float lw = -softplusf(-dw);
    lwS[l]  = lw;
    clmS[l] = lm;
    cwdS[l] = lw;
    __syncthreads();

    for (int off = 1; off < Lc; off <<= 1) {
        float a = (l >= off) ? clmS[l - off] : 0.f;
        float c = (l >= off) ? cwdS[l - off] : 0.f;
        __syncthreads();
        clmS[l] += a; cwdS[l] += c;
        __syncthreads();
    }
    wdf[b * Lc + l] = expf(cwdS[l]);
    ewdS[l] = __expf(lwS[l]);
    __syncthreads();

    const int   m     = l;
    const float clm_m = clmS[m];
    const float lrm   = lrS[m];
    float* outp = Ssc + (b * Lc) * Lc + m;
    float s = 0.f;
    for (int ll = 0; ll < Lc; ++ll) {
        float e2 = __expf(clmS[ll] - clm_m);
        s = (ll >= m) ? (ewdS[ll] * s + e2) : 0.f;
        outp[ll * Lc] = s * lrm;
    }
}

// ---------------------------------------------------------------------------
// K1: per-token forward + gradients. 128 blocks x 256 threads, 4 tokens/block.
// ---------------------------------------------------------------------------
__global__ __launch_bounds__(256) void k_token(
    const float* __restrict__ x,
    const float* __restrict__ b1v, const float* __restrict__ b2v,
    const float* __restrict__ bq,  const float* __restrict__ bk,
    const float* __restrict__ bv,
    const float4* __restrict__ Wq4, const float4* __restrict__ Wk4,
    const float4* __restrict__ Wv4, const float4* __restrict__ W14,
    const float4* __restrict__ W2q4, const float4* __restrict__ W2c4,
    float* __restrict__ qo, float4* __restrict__ KT4, float4* __restrict__ X2T4,
    float* __restrict__ z1q, float4* __restrict__ GZ1q, float4* __restrict__ GZ2q)
{
    __shared__ __align__(16) float xs[Tt][Dc], qs[Tt][Dc], ks[Tt][Dc];
    __shared__ __align__(16) float X2s[Tt][Hc];
    __shared__ __align__(16) float pz[2][Tt][Dc], pv[2][Tt][Dc], gZ2s[Tt][Dc];

    const int t0  = blockIdx.x * Tt;
    const int b   = t0 >> 8;
    const int l0  = t0 & 255;
    const int tid = threadIdx.x;

    if (tid < Tt * Dc / 4)
        ((float4*)&xs[0][0])[tid] = ((const float4*)(x + t0 * Dc))[tid];
    __syncthreads();

    // --- phase 1: q + v-half (threads 0..127) | k + v-half (threads 128..255)
    {
        const int hf = tid >> 7;
        const int c  = tid & 127;
        float a[Tt], av[Tt] = {0.f, 0.f, 0.f, 0.f};
        const float4* Wmain = hf ? Wk4 : Wq4;
        const float*  bmain = hf ? bk  : bq;
        #pragma unroll
        for (int t = 0; t < Tt; ++t) a[t] = bmain[c];
        #pragma unroll 4
        for (int j4 = 0; j4 < 32; ++j4) {
            float4 w = Wmain[j4 * Dc + c];
            #pragma unroll
            for (int t = 0; t < Tt; ++t)
                a[t] += dot4(w, *(const float4*)&xs[t][4*j4]);
        }
        const int v0 = hf * 16;
        #pragma unroll 4
        for (int j4 = v0; j4 < v0 + 16; ++j4) {
            float4 w = Wv4[j4 * Dc + c];
            #pragma unroll
            for (int t = 0; t < Tt; ++t)
                av[t] += dot4(w, *(const float4*)&xs[t][4*j4]);
        }
        #pragma unroll
        for (int t = 0; t < Tt; ++t) pv[hf][t][c] = av[t];
        if (hf == 0) {
            #pragma unroll
            for (int t = 0; t < Tt; ++t) {
                qs[t][c] = a[t];
                qo[(t0 + t) * Dc + c] = a[t];
            }
        } else {
            #pragma unroll
            for (int t = 0; t < Tt; ++t) ks[t][c] = a[t];
            float* ktp = (float*)(KT4 + (size_t)b * 8192);
            #pragma unroll
            for (int t = 0; t < Tt; ++t)
                ktp[(((c >> 2) * Lc) + l0 + t) * 4 + (c & 3)] = a[t];
        }
    }
    __syncthreads();

    // --- phase 2: Z1 (from k) and z1q (from q); X2 = silu(Z1) ---
    float z1r[Tt];
    {
        const int h = tid;
        const float bb1 = b1v[h];
        float a[Tt], aq[Tt];
        #pragma unroll
        for (int t = 0; t < Tt; ++t) { a[t] = bb1; aq[t] = bb1; }
        #pragma unroll 4
        for (int d4 = 0; d4 < 32; ++d4) {
            float4 w = W14[d4 * Hc + h];
            #pragma unroll
            for (int t = 0; t < Tt; ++t) {
                a[t]  += dot4(w, *(const float4*)&ks[t][4*d4]);
                aq[t] += dot4(w, *(const float4*)&qs[t][4*d4]);
            }
        }
        float* xtp = (float*)(X2T4 + (size_t)b * 16384);
        #pragma unroll
        for (int t = 0; t < Tt; ++t) {
            z1r[t] = a[t];
            float s = siluf(a[t]);
            X2s[t][h] = s;
            z1q[(t0 + t) * Hc + h] = aq[t];
            xtp[(((h >> 2) * Lc) + l0 + t) * 4 + (h & 3)] = s;
        }
    }
    __syncthreads();

    // --- phase 3: Z2 halves ---
    {
        const int d = tid & 127, hf = tid >> 7;
        float a[Tt] = {0.f, 0.f, 0.f, 0.f};
        const int h0 = hf * 32;
        #pragma unroll 4
        for (int h4 = h0; h4 < h0 + 32; ++h4) {
            float4 w = W2q4[h4 * Dc + d];
            #pragma unroll
            for (int t = 0; t < Tt; ++t)
                a[t] += dot4(w, *(const float4*)&X2s[t][4*h4]);
        }
        #pragma unroll
        for (int t = 0; t < Tt; ++t) pz[hf][t][d] = a[t];
    }
    __syncthreads();
    if (tid < Dc) {
        const int d = tid;
        float g[Tt];
        #pragma unroll
        for (int t = 0; t < Tt; ++t) {
            g[t] = pz[0][t][d] + pz[1][t][d] + b2v[d]
                 - (pv[0][t][d] + pv[1][t][d] + bv[d]);
            gZ2s[t][d] = g[t];
        }
        GZ2q[(size_t)b * 8192 + (l0 >> 2) * Dc + d]
            = make_float4(g[0], g[1], g[2], g[3]);
    }
    __syncthreads();

    // --- phase 4: gX2 via W2 column-groups; gZ1 = gX2 * silu_bwd(Z1) ---
    {
        const int h = tid;
        float a[Tt] = {0.f, 0.f, 0.f, 0.f};
        #pragma unroll 4
        for (int d4 = 0; d4 < 32; ++d4) {
            float4 w = W2c4[d4 * Hc + h];
            #pragma unroll
            for (int t = 0; t < Tt; ++t)
                a[t] += dot4(w, *(const float4*)&gZ2s[t][4*d4]);
        }
        float v[Tt];
        #pragma unroll
        for (int t = 0; t < Tt; ++t) v[t] = a[t] * silubwdf(z1r[t]);
        GZ1q[(size_t)b * 16384 + (l0 >> 2) * Hc + h]
            = make_float4(v[0], v[1], v[2], v[3]);
    }
}

// ---------------------------------------------------------------------------
// K2: fused query. 128 blocks x 256 threads, 4 tokens/block.
// ---------------------------------------------------------------------------
__global__ __launch_bounds__(256) void k_query(
    const float* __restrict__ qo,  const float4* __restrict__ KT4,
    const float4* __restrict__ X2T4, const float4* __restrict__ GZ1q,
    const float4* __restrict__ GZ2q, const float* __restrict__ z1q,
    const float* __restrict__ Ssc, const float* __restrict__ wdf,
    const float4* __restrict__ W2q4, const float* __restrict__ b2v,
    float* __restrict__ out)
{
    __shared__ __align__(16) float qs[Tt][Dc];
    __shared__ __align__(16) float ssS[Tt][Lc], arow[Tt][Lc];
    __shared__ __align__(16) float xq2s[Tt][Hc];
    __shared__ __align__(16) float pm[2][Tt][Dc], pw[2][Tt][Dc];

    const int t0  = blockIdx.x * Tt;
    const int b   = t0 >> 8;
    const int tid = threadIdx.x;

    if (tid < Tt * Dc / 4)
        ((float4*)&qs[0][0])[tid] = ((const float4*)(qo + t0 * Dc))[tid];
    float wdfv[Tt];
    #pragma unroll
    for (int t = 0; t < Tt; ++t) wdfv[t] = wdf[t0 + t];
    {
        const int m = tid;
        #pragma unroll
        for (int t = 0; t < Tt; ++t) ssS[t][m] = Ssc[(t0 + t) * Lc + m];
    }
    __syncthreads();

    // --- score1 ---
    {
        const int m = tid;
        const float4* ktb = KT4 + (size_t)b * 8192;
        float acc[Tt] = {0.f, 0.f, 0.f, 0.f};
        #pragma unroll 4
        for (int d4 = 0; d4 < 32; ++d4) {
            float4 kv = ktb[d4 * Lc + m];
            #pragma unroll
            for (int t = 0; t < Tt; ++t)
                acc[t] += dot4(kv, *(const float4*)&qs[t][4*d4]);
        }
        #pragma unroll
        for (int t = 0; t < Tt; ++t)
            arow[t][m] = ssS[t][m] * (acc[t] + 1.f);
    }
    __syncthreads();

    // --- Zq1 + silu ---
    {
        const int h = tid;
        const float4* g = GZ1q + (size_t)b * 16384;
        float acc[Tt] = {0.f, 0.f, 0.f, 0.f};
        #pragma unroll 4
        for (int m4 = 0; m4 < 64; ++m4) {
            float4 gv = g[m4 * Hc + h];
            #pragma unroll
            for (int t = 0; t < Tt; ++t)
                acc[t] += dot4(gv, *(const float4*)&arow[t][4*m4]);
        }
        #pragma unroll
        for (int t = 0; t < Tt; ++t) {
            float z = acc[t] + wdfv[t] * z1q[(t0 + t) * Hc + h];
            xq2s[t][h] = siluf(z);
        }
    }
    __syncthreads();

    // --- score2 ---
    {
        const int m = tid;
        const float4* xtb = X2T4 + (size_t)b * 16384;
        float acc[Tt] = {0.f, 0.f, 0.f, 0.f};
        #pragma unroll 4
        for (int h4 = 0; h4 < 64; ++h4) {
            float4 xv = xtb[h4 * Lc + m];
            #pragma unroll
            for (int t = 0; t < Tt; ++t)
                acc[t] += dot4(xv, *(const float4*)&xq2s[t][4*h4]);
        }
        __syncthreads();   // all arow reads (Zq1) done before overwrite
        #pragma unroll
        for (int t = 0; t < Tt; ++t)
            arow[t][m] = ssS[t][m] * (acc[t] + 1.f);
    }
    __syncthreads();

    // --- Zq2 halves ---
    {
        const int d = tid & 127, hf = tid >> 7;
        const int c0 = hf * 32;
        float am[Tt] = {0.f, 0.f, 0.f, 0.f};
        float aw[Tt] = {0.f, 0.f, 0.f, 0.f};
        const float4* g2 = GZ2q + (size_t)b * 8192;
        #pragma unroll 4
        for (int m4 = c0; m4 < c0 + 32; ++m4) {
            float4 gv = g2[m4 * Dc + d];
            #pragma unroll
            for (int t = 0; t < Tt; ++t)
                am[t] += dot4(gv, *(const float4*)&arow[t][4*m4]);
        }
        #pragma unroll 4
        for (int h4 = c0; h4 < c0 + 32; ++h4) {
            float4 w = W2q4[h4 * Dc + d];
            #pragma unroll
            for (int t = 0; t < Tt; ++t)
                aw[t] += dot4(w, *(const float4*)&xq2s[t][4*h4]);
        }
        #pragma unroll
        for (int t = 0; t < Tt; ++t) { pm[hf][t][d] = am[t]; pw[hf][t][d] = aw[t]; }
    }
    __syncthreads();
    if (tid < Dc) {
        const int d = tid;
        #pragma unroll
        for (int t = 0; t < Tt; ++t)
            out[(t0 + t) * Dc + d] = (pm[0][t][d] + pm[1][t][d])
                + wdfv[t] * (b2v[d] + pw[0][t][d] + pw[1][t][d]);
    }
}

// ---------------------------------------------------------------------------
extern "C" void kernel_launch(void* const* d_in, const int* in_sizes, int n_in,
                              void* d_out, int out_size, void* d_ws, size_t ws_size,
                              hipStream_t stream)
{
    const float* x   = (const float*)d_in[0];
    const float* W1  = (const float*)d_in[1];
    const float* b1  = (const float*)d_in[2];
    const float* W2  = (const float*)d_in[3];
    const float* b2  = (const float*)d_in[4];
    const float* Wq  = (const float*)d_in[5];
    const float* bq  = (const float*)d_in[6];
    const float* Wk  = (const float*)d_in[7];
    const float* bk  = (const float*)d_in[8];
    const float* Wv  = (const float*)d_in[9];
    const float* bv  = (const float*)d_in[10];
    const float* Wlr = (const float*)d_in[11];
    const float* blr = (const float*)d_in[12];
    const float* Wm  = (const float*)d_in[13];
    const float* bm  = (const float*)d_in[14];
    const float* Wwd = (const float*)d_in[15];
    const float* bwd = (const float*)d_in[16];

    float* ws = (float*)d_ws;
    float*  qo   = ws;                       // 65536
    float4* KT4  = (float4*)(ws + 65536);    // 65536 floats
    float4* X2T4 = (float4*)(ws + 131072);   // 131072 floats
    float4* GZ1q = (float4*)(ws + 262144);   // 131072 floats
    float4* GZ2q = (float4*)(ws + 393216);   // 65536 floats
    float*  z1q  = ws + 458752;              // 131072
    float*  Ssc  = ws + 589824;              // 131072
    float*  wdf  = ws + 720896;              // 512
    float4* Wq4  = (float4*)(ws + 721408);   // 16384 floats
    float4* Wk4  = (float4*)(ws + 737792);   // 16384
    float4* Wv4  = (float4*)(ws + 754176);   // 16384
    float4* W14  = (float4*)(ws + 770560);   // 32768
    float4* W2q4 = (float4*)(ws + 803328);   // 32768
    float4* W2c4 = (float4*)(ws + 836096);   // 32768
    float*  out  = (float*)d_out;

    k_pre<<<146, 256, 0, stream>>>(Wq, Wk, Wv, W1, W2,
                                   Wq4, Wk4, Wv4, W14, W2q4, W2c4,
                                   x, Wlr, blr, Wm, bm, Wwd, bwd, Ssc, wdf);
    k_token<<<Bc*Lc/Tt, 256, 0, stream>>>(x, b1, b2, bq, bk, bv,
                                          Wq4, Wk4, Wv4, W14, W2q4, W2c4,
                                          qo, KT4, X2T4, z1q, GZ1q, GZ2q);
    k_query<<<Bc*Lc/Tt, 256, 0, stream>>>(qo, KT4, X2T4, GZ1q, GZ2q, z1q,
                                          Ssc, wdf, W2q4, b2, out);
}